// Round 1
// baseline (371.973 us; speedup 1.0000x reference)
//
#include <hip/hip_runtime.h>
#include <stdint.h>

#define NL   12
#define PTOT 32936
#define LMB  32778
#define NCH  515          // ceil(PTOT/64)
#define NCHP 520          // padded (zeroed) chunk words
#define PPAD (NCH * 64)   // 32960

__device__ __constant__ int c_base[NL] = {0,86,653,1701,3230,5240,7731,10703,14156,18090,22505,27401};

__device__ __forceinline__ uint64_t ext(const uint64_t* P, uint32_t off) {
  uint32_t w = off >> 6, s = off & 63;
  uint64_t lo = P[w], hi = P[w + 1];
  return s ? ((lo >> s) | (hi << (64 - s))) : lo;
}

__device__ __forceinline__ uint64_t rbit(uint64_t r0, uint64_t r1, uint64_t r2, uint32_t idx) {
  uint64_t w = idx < 64 ? r0 : (idx < 128 ? r1 : r2);
  return (w >> (idx & 63)) & 1ull;
}

__device__ __forceinline__ void orAt(uint64_t& r0, uint64_t& r1, uint64_t& r2,
                                     uint64_t val, uint32_t pos) {
  uint32_t w = pos >> 6, s = pos & 63;
  uint64_t lo = val << s;
  uint64_t hi = s ? (val >> (64 - s)) : 0ull;
  if (w == 0) { r0 |= lo; r1 |= hi; }
  else if (w == 1) { r1 |= lo; r2 |= hi; }
  else { r2 |= lo; }
}

__device__ __forceinline__ void maskLen(uint32_t len, uint64_t& m0, uint64_t& m1, uint64_t& m2) {
  m0 = (len >= 64) ? ~0ull : ((1ull << len) - 1ull);
  m1 = (len <= 64) ? 0ull : ((len >= 128) ? ~0ull : ((1ull << (len - 64)) - 1ull));
  m2 = (len <= 128) ? 0ull : ((1ull << (len - 128)) - 1ull);
}

__device__ __forceinline__ uint32_t ext12(uint64_t O0, uint64_t O1, uint64_t O2, uint32_t pos) {
  uint32_t w = pos >> 6, s = pos & 63;
  uint64_t lo = (w == 0) ? O0 : ((w == 1) ? O1 : O2);
  uint64_t hi = (w == 0) ? O1 : ((w == 1) ? O2 : 0ull);
  uint64_t v = s ? ((lo >> s) | (hi << (64 - s))) : lo;
  return (uint32_t)v & 0xFFFu;
}

// Build per-param (prob', window) and packed (outv|inv<<8) vertex table.
__global__ void init_tables(const float* __restrict__ sp, float2* __restrict__ pw,
                            unsigned short* __restrict__ vtx) {
  int p = blockIdx.x * blockDim.x + threadIdx.x;
  if (p >= PPAD) return;
  if (p < PTOT) {
    float x = sp[p];
    float s = 1.0f / (1.0f + expf(-x));                 // sigmoid, fp32
    float w = __fmul_rn(s, __fsub_rn(1.0f, s));         // window = p*(1-p), exact rn
    // prob' = w*p + (1-w)*p, replicated with rn ops (blocks fp-contract)
    float pr = __fadd_rn(__fmul_rn(w, s), __fmul_rn(__fsub_rn(1.0f, w), s));
    pw[p] = make_float2(pr, w);
    int outv, inv;
    if (p >= LMB) { outv = p - LMB; inv = outv; }
    else {
      int L = 0;
#pragma unroll
      for (int i = 1; i < NL; ++i) if (p >= c_base[i]) L = i;
      int Vq  = 2 + 13 * L;            // == a0
      int off = p - c_base[L];
      int nq  = 36 * Vq;
      if (off < nq) { int g = off / Vq; inv = off - g * Vq; outv = Vq + (g % 12); }
      else          { outv = Vq + 12; inv = off - nq; }
    }
    vtx[p] = (unsigned short)(outv | (inv << 8));
  } else {
    pw[p]  = make_float2(0.0f, 1.0f);
    vtx[p] = 0;
  }
}

__global__ __launch_bounds__(256) void mask_kernel(const float* __restrict__ unif,
                                                   const float2* __restrict__ pw,
                                                   const unsigned short* __restrict__ vtx,
                                                   float* __restrict__ out) {
  __shared__ uint64_t sPos[NCHP];   // pos from original masks
  __shared__ uint64_t sPos2[NCHP];  // pos after forward prune
  __shared__ uint32_t sR[6], sO[6];

  const int tid  = threadIdx.x;
  const int lane = tid & 63;
  const int wv   = tid >> 6;
  const int row  = blockIdx.x;
  const float* up = unif + (size_t)row * PTOT;
  float*       op = out  + (size_t)row * PTOT;

  // ---- Phase 1: masks values -> out, positivity bits -> LDS -------------
  for (int c = wv; c < NCHP; c += 4) {
    int p = c * 64 + lane;
    bool inb = p < PTOT;
    float u = 0.0f, pr = 0.0f, wd = 1.0f;
    if (inb) { u = up[p]; float2 t = pw[p]; pr = t.x; wd = t.y; }
    // m = (prob - unif)/window + 0.5 with reference rounding (div cannot contract)
    float m = __fadd_rn(__fdiv_rn(__fsub_rn(pr, u), wd), 0.5f);
    if (inb) op[p] = fminf(fmaxf(m, 0.0f), 1.0f);
    uint64_t bal = __ballot(inb && (m > 0.0f));
    if (lane == 0) { sPos[c] = bal; sPos2[c] = bal; }
  }
  __syncthreads();

  // ---- Phase 2: forward reachability (wave 0) ---------------------------
  if (tid < 64) {
    uint64_t R0 = 3ull, R1 = 0ull, R2 = 0ull;   // vertices 0,1 reachable
    const int g = lane;
#pragma unroll
    for (int L = 0; L < NL; ++L) {
      const int Vq = 2 + 13 * L;
      const int b  = c_base[L];
      bool pred = false;
      if (g < 36) {
        uint32_t off = (uint32_t)(b + g * Vq);
        uint64_t e0 = ext(sPos, off), e1 = ext(sPos, off + 64), e2 = ext(sPos, off + 128);
        pred = ((e0 & R0) | (e1 & R1) | (e2 & R2)) != 0ull;   // R has only Vq bits
      }
      uint64_t bal = __ballot(pred);
      uint64_t ar  = bal & (bal >> 12) & (bal >> 24) & 0xFFFull;   // all-of-q,k,v
      orAt(R0, R1, R2, ar, (uint32_t)Vq);
      const int Vm = Vq + 12;
      uint32_t offm = (uint32_t)(b + 36 * Vq);
      uint64_t e0 = ext(sPos, offm), e1 = ext(sPos, offm + 64), e2 = ext(sPos, offm + 128);
      uint64_t mr = (((e0 & R0) | (e1 & R1) | (e2 & R2)) != 0ull) ? 1ull : 0ull;
      orAt(R0, R1, R2, mr, (uint32_t)Vm);
    }
    if (lane == 0) {
      sR[0] = (uint32_t)R0; sR[1] = (uint32_t)(R0 >> 32);
      sR[2] = (uint32_t)R1; sR[3] = (uint32_t)(R1 >> 32);
      sR[4] = (uint32_t)R2; sR[5] = (uint32_t)(R2 >> 32);
    }
  }
  __syncthreads();

  // ---- Phase 2b: apply forward keep to pos2 (all threads) ---------------
  {
    uint64_t r0 = ((uint64_t)sR[1] << 32) | sR[0];
    uint64_t r1 = ((uint64_t)sR[3] << 32) | sR[2];
    uint64_t r2 = ((uint64_t)sR[5] << 32) | sR[4];
    const uint32_t* vt32 = (const uint32_t*)vtx;
    for (int w = tid; w < NCH; w += 256) {
      uint64_t pm = sPos2[w];
      if (!pm) continue;
      const uint32_t* vp = vt32 + w * 32;
      uint64_t keep = 0ull;
#pragma unroll 8
      for (int j = 0; j < 32; ++j) {
        uint32_t e = vp[j];
        uint64_t k0 = rbit(r0, r1, r2, e & 0xFFu)         & rbit(r0, r1, r2, (e >> 8) & 0xFFu);
        uint64_t k1 = rbit(r0, r1, r2, (e >> 16) & 0xFFu) & rbit(r0, r1, r2, e >> 24);
        keep |= (k0 << (2 * j)) | (k1 << (2 * j + 1));
      }
      sPos2[w] = pm & keep;
    }
  }
  __syncthreads();

  // ---- Phase 3: backward liveness (wave 0) ------------------------------
  if (tid < 64) {
    uint64_t O0 = ext(sPos2, LMB);
    uint64_t O1 = ext(sPos2, LMB + 64);
    uint64_t O2 = ext(sPos2, LMB + 128) & ((1ull << 30) - 1ull);
    const int g  = lane;
    const int hg = g % 12;
#pragma unroll
    for (int L = NL - 1; L >= 0; --L) {
      const int Vq = 2 + 13 * L, Vm = Vq + 12;
      const int b  = c_base[L];
      // mlp edges feed inputs if the mlp vertex (a0+H == Vm) is live
      if (rbit(O0, O1, O2, (uint32_t)Vm)) {
        uint64_t m0, m1, m2; maskLen((uint32_t)Vm, m0, m1, m2);
        uint32_t offm = (uint32_t)(b + 36 * Vq);
        O0 |= ext(sPos2, offm)       & m0;
        O1 |= ext(sPos2, offm + 64)  & m1;
        O2 |= ext(sPos2, offm + 128) & m2;
      }
      // qkv: any live head with a positive edge makes input vertex live
      uint32_t h12 = ext12(O0, O1, O2, (uint32_t)Vq);   // heads at a0..a0+11
      uint64_t q0, q1, q2; maskLen((uint32_t)Vq, q0, q1, q2);
      uint64_t c0 = 0ull, c1 = 0ull, c2 = 0ull;
      if (g < 36 && ((h12 >> hg) & 1u)) {
        uint32_t off = (uint32_t)(b + g * Vq);
        c0 = ext(sPos2, off)       & q0;
        c1 = ext(sPos2, off + 64)  & q1;
        c2 = ext(sPos2, off + 128) & q2;
      }
#pragma unroll
      for (int d = 32; d; d >>= 1) {
        c0 |= __shfl_xor((unsigned long long)c0, d);
        c1 |= __shfl_xor((unsigned long long)c1, d);
        c2 |= __shfl_xor((unsigned long long)c2, d);
      }
      O0 |= c0; O1 |= c1; O2 |= c2;
    }
    if (lane == 0) {
      sO[0] = (uint32_t)O0; sO[1] = (uint32_t)(O0 >> 32);
      sO[2] = (uint32_t)O1; sO[3] = (uint32_t)(O1 >> 32);
      sO[4] = (uint32_t)O2; sO[5] = (uint32_t)(O2 >> 32);
    }
  }
  __syncthreads();

  // ---- Phase 4: zero pruned-but-written outputs -------------------------
  {
    uint64_t o0 = ((uint64_t)sO[1] << 32) | sO[0];
    uint64_t o1 = ((uint64_t)sO[3] << 32) | sO[2];
    uint64_t o2 = ((uint64_t)sO[5] << 32) | sO[4];
    const uint32_t* vt32 = (const uint32_t*)vtx;
    for (int w = tid; w < NCH; w += 256) {
      uint64_t pm = sPos[w];
      if (!pm) continue;
      uint64_t p2 = sPos2[w];
      const uint32_t* vp = vt32 + w * 32;
      uint64_t keep = 0ull;
#pragma unroll 8
      for (int j = 0; j < 32; ++j) {
        uint32_t e = vp[j];
        uint64_t k0 = rbit(o0, o1, o2, e & 0xFFu)         & rbit(o0, o1, o2, (e >> 8) & 0xFFu);
        uint64_t k1 = rbit(o0, o1, o2, (e >> 16) & 0xFFu) & rbit(o0, o1, o2, e >> 24);
        keep |= (k0 << (2 * j)) | (k1 << (2 * j + 1));
      }
      uint64_t z = pm & ~(p2 & keep);   // was >0 but pruned -> write 0
      while (z) {
        int i = __builtin_ctzll(z);
        z &= z - 1;
        op[w * 64 + i] = 0.0f;
      }
    }
  }
}

extern "C" void kernel_launch(void* const* d_in, const int* in_sizes, int n_in,
                              void* d_out, int out_size, void* d_ws, size_t ws_size,
                              hipStream_t stream) {
  const float* sp   = (const float*)d_in[0];
  const float* unif = (const float*)d_in[1];
  float* out = (float*)d_out;
  float2* pw = (float2*)d_ws;
  unsigned short* vtx = (unsigned short*)((char*)d_ws + (size_t)PPAD * sizeof(float2));
  int bz = in_sizes[1] / PTOT;   // 1024
  init_tables<<<dim3((PPAD + 255) / 256), dim3(256), 0, stream>>>(sp, pw, vtx);
  mask_kernel<<<dim3(bz), dim3(256), 0, stream>>>(unif, pw, vtx, out);
}

// Round 2
// 338.754 us; speedup vs baseline: 1.0981x; 1.0981x over previous
//
#include <hip/hip_runtime.h>
#include <stdint.h>

#define NL   12
#define PTOT 32936
#define LMB  32778
#define NCH  515          // ceil(PTOT/64)
#define NCHP 520          // padded (zeroed) chunk words in LDS
#define PPAD (NCH * 64)   // 32960
#define CPW  4            // chunks per wave in the streaming kernel

__device__ __constant__ int c_base[NL] = {0,86,653,1701,3230,5240,7731,10703,14156,18090,22505,27401};

__device__ __forceinline__ uint64_t ext(const uint64_t* P, uint32_t off) {
  uint32_t w = off >> 6, s = off & 63;
  uint64_t lo = P[w], hi = P[w + 1];
  return s ? ((lo >> s) | (hi << (64 - s))) : lo;
}

__device__ __forceinline__ uint64_t rbit(uint64_t r0, uint64_t r1, uint64_t r2, uint32_t idx) {
  uint64_t w = idx < 64 ? r0 : (idx < 128 ? r1 : r2);
  return (w >> (idx & 63)) & 1ull;
}

__device__ __forceinline__ void orAt(uint64_t& r0, uint64_t& r1, uint64_t& r2,
                                     uint64_t val, uint32_t pos) {
  uint32_t w = pos >> 6, s = pos & 63;
  uint64_t lo = val << s;
  uint64_t hi = s ? (val >> (64 - s)) : 0ull;
  if (w == 0) { r0 |= lo; r1 |= hi; }
  else if (w == 1) { r1 |= lo; r2 |= hi; }
  else { r2 |= lo; }
}

__device__ __forceinline__ void maskLen(uint32_t len, uint64_t& m0, uint64_t& m1, uint64_t& m2) {
  m0 = (len >= 64) ? ~0ull : ((1ull << len) - 1ull);
  m1 = (len <= 64) ? 0ull : ((len >= 128) ? ~0ull : ((1ull << (len - 64)) - 1ull));
  m2 = (len <= 128) ? 0ull : ((1ull << (len - 128)) - 1ull);
}

__device__ __forceinline__ uint32_t ext12(uint64_t O0, uint64_t O1, uint64_t O2, uint32_t pos) {
  uint32_t w = pos >> 6, s = pos & 63;
  uint64_t lo = (w == 0) ? O0 : ((w == 1) ? O1 : O2);
  uint64_t hi = (w == 0) ? O1 : ((w == 1) ? O2 : 0ull);
  uint64_t v = s ? ((lo >> s) | (hi << (64 - s))) : lo;
  return (uint32_t)v & 0xFFFu;
}

// Build per-param (prob', window) and packed (outv|inv<<8) vertex table.
__global__ void init_tables(const float* __restrict__ sp, float2* __restrict__ pw,
                            unsigned short* __restrict__ vtx) {
  int p = blockIdx.x * blockDim.x + threadIdx.x;
  if (p >= PPAD) return;
  if (p < PTOT) {
    float x = sp[p];
    float s = 1.0f / (1.0f + expf(-x));                 // sigmoid, fp32
    float w = __fmul_rn(s, __fsub_rn(1.0f, s));         // window = p*(1-p), exact rn
    float pr = __fadd_rn(__fmul_rn(w, s), __fmul_rn(__fsub_rn(1.0f, w), s));
    pw[p] = make_float2(pr, w);
    int outv, inv;
    if (p >= LMB) { outv = p - LMB; inv = outv; }
    else {
      int L = 0;
#pragma unroll
      for (int i = 1; i < NL; ++i) if (p >= c_base[i]) L = i;
      int Vq  = 2 + 13 * L;            // == a0
      int off = p - c_base[L];
      int nq  = 36 * Vq;
      if (off < nq) { int g = off / Vq; inv = off - g * Vq; outv = Vq + (g % 12); }
      else          { outv = Vq + 12; inv = off - nq; }
    }
    vtx[p] = (unsigned short)(outv | (inv << 8));
  } else {
    pw[p]  = make_float2(0.0f, 1.0f);
    vtx[p] = 0;
  }
}

// ---- Kernel A: fully-parallel streaming: masks -> out, pos bits -> bm ----
__global__ __launch_bounds__(256) void sample_kernel(const float* __restrict__ unif,
                                                     const float2* __restrict__ pw,
                                                     float* __restrict__ out,
                                                     uint64_t* __restrict__ bm) {
  const int lane = threadIdx.x & 63;
  const int wv   = threadIdx.x >> 6;
  const int row  = blockIdx.y;
  const int ch0  = (blockIdx.x * 4 + wv) * CPW;
  const float*    up = unif + (size_t)row * PTOT;
  float*          op = out  + (size_t)row * PTOT;
  uint64_t*       bp = bm   + (size_t)row * NCH;
#pragma unroll
  for (int k = 0; k < CPW; ++k) {
    int c = ch0 + k;
    if (c >= NCH) break;
    int p = c * 64 + lane;
    bool inb = p < PTOT;
    float u = 0.0f, pr = 0.0f, wd = 1.0f;
    if (inb) { u = up[p]; float2 t = pw[p]; pr = t.x; wd = t.y; }
    // m = (prob - unif)/window + 0.5, reference fp32 rounding (no contraction)
    float m = __fadd_rn(__fdiv_rn(__fsub_rn(pr, u), wd), 0.5f);
    if (inb) op[p] = fminf(fmaxf(m, 0.0f), 1.0f);
    uint64_t bal = __ballot(inb && (m > 0.0f));
    if (lane == 0) bp[c] = bal;
  }
}

// ---- Kernel B: per-row graph prune, scatter-zero pruned outputs ----------
__global__ __launch_bounds__(256) void prune_kernel(const uint64_t* __restrict__ bm,
                                                    const unsigned short* __restrict__ vtx,
                                                    float* __restrict__ out) {
  __shared__ uint64_t sPos[NCHP];   // pos from original masks
  __shared__ uint64_t sPos2[NCHP];  // pos after forward prune
  __shared__ uint32_t sR[6], sO[6];

  const int tid  = threadIdx.x;
  const int lane = tid & 63;
  const int row  = blockIdx.x;
  const uint64_t* bp = bm  + (size_t)row * NCH;
  float*           op = out + (size_t)row * PTOT;

  for (int w = tid; w < NCHP; w += 256) {
    uint64_t v = (w < NCH) ? bp[w] : 0ull;
    sPos[w] = v; sPos2[w] = v;
  }
  __syncthreads();

  // ---- Phase 2: forward reachability (wave 0) ---------------------------
  if (tid < 64) {
    uint64_t R0 = 3ull, R1 = 0ull, R2 = 0ull;   // vertices 0,1 reachable
    const int g = lane;
#pragma unroll
    for (int L = 0; L < NL; ++L) {
      const int Vq = 2 + 13 * L;
      const int b  = c_base[L];
      bool pred = false;
      if (g < 36) {
        uint32_t off = (uint32_t)(b + g * Vq);
        uint64_t e0 = ext(sPos, off), e1 = ext(sPos, off + 64), e2 = ext(sPos, off + 128);
        pred = ((e0 & R0) | (e1 & R1) | (e2 & R2)) != 0ull;   // R has only Vq bits
      }
      uint64_t bal = __ballot(pred);
      uint64_t ar  = bal & (bal >> 12) & (bal >> 24) & 0xFFFull;   // all-of-q,k,v
      orAt(R0, R1, R2, ar, (uint32_t)Vq);
      const int Vm = Vq + 12;
      uint32_t offm = (uint32_t)(b + 36 * Vq);
      uint64_t e0 = ext(sPos, offm), e1 = ext(sPos, offm + 64), e2 = ext(sPos, offm + 128);
      uint64_t mr = (((e0 & R0) | (e1 & R1) | (e2 & R2)) != 0ull) ? 1ull : 0ull;
      orAt(R0, R1, R2, mr, (uint32_t)Vm);
    }
    if (lane == 0) {
      sR[0] = (uint32_t)R0; sR[1] = (uint32_t)(R0 >> 32);
      sR[2] = (uint32_t)R1; sR[3] = (uint32_t)(R1 >> 32);
      sR[4] = (uint32_t)R2; sR[5] = (uint32_t)(R2 >> 32);
    }
  }
  __syncthreads();

  // ---- Phase 2b: apply forward keep to pos2 (all threads) ---------------
  {
    uint64_t r0 = ((uint64_t)sR[1] << 32) | sR[0];
    uint64_t r1 = ((uint64_t)sR[3] << 32) | sR[2];
    uint64_t r2 = ((uint64_t)sR[5] << 32) | sR[4];
    const uint32_t* vt32 = (const uint32_t*)vtx;
    for (int w = tid; w < NCH; w += 256) {
      uint64_t pm = sPos2[w];
      if (!pm) continue;
      const uint32_t* vp = vt32 + w * 32;
      uint64_t keep = 0ull;
#pragma unroll 8
      for (int j = 0; j < 32; ++j) {
        uint32_t e = vp[j];
        uint64_t k0 = rbit(r0, r1, r2, e & 0xFFu)         & rbit(r0, r1, r2, (e >> 8) & 0xFFu);
        uint64_t k1 = rbit(r0, r1, r2, (e >> 16) & 0xFFu) & rbit(r0, r1, r2, e >> 24);
        keep |= (k0 << (2 * j)) | (k1 << (2 * j + 1));
      }
      sPos2[w] = pm & keep;
    }
  }
  __syncthreads();

  // ---- Phase 3: backward liveness (wave 0) ------------------------------
  if (tid < 64) {
    uint64_t O0 = ext(sPos2, LMB);
    uint64_t O1 = ext(sPos2, LMB + 64);
    uint64_t O2 = ext(sPos2, LMB + 128) & ((1ull << 30) - 1ull);
    const int g  = lane;
    const int hg = g % 12;
#pragma unroll
    for (int L = NL - 1; L >= 0; --L) {
      const int Vq = 2 + 13 * L, Vm = Vq + 12;
      const int b  = c_base[L];
      if (rbit(O0, O1, O2, (uint32_t)Vm)) {
        uint64_t m0, m1, m2; maskLen((uint32_t)Vm, m0, m1, m2);
        uint32_t offm = (uint32_t)(b + 36 * Vq);
        O0 |= ext(sPos2, offm)       & m0;
        O1 |= ext(sPos2, offm + 64)  & m1;
        O2 |= ext(sPos2, offm + 128) & m2;
      }
      uint32_t h12 = ext12(O0, O1, O2, (uint32_t)Vq);   // heads at a0..a0+11
      uint64_t q0, q1, q2; maskLen((uint32_t)Vq, q0, q1, q2);
      uint64_t c0 = 0ull, c1 = 0ull, c2 = 0ull;
      if (g < 36 && ((h12 >> hg) & 1u)) {
        uint32_t off = (uint32_t)(b + g * Vq);
        c0 = ext(sPos2, off)       & q0;
        c1 = ext(sPos2, off + 64)  & q1;
        c2 = ext(sPos2, off + 128) & q2;
      }
#pragma unroll
      for (int d = 32; d; d >>= 1) {
        c0 |= __shfl_xor((unsigned long long)c0, d);
        c1 |= __shfl_xor((unsigned long long)c1, d);
        c2 |= __shfl_xor((unsigned long long)c2, d);
      }
      O0 |= c0; O1 |= c1; O2 |= c2;
    }
    if (lane == 0) {
      sO[0] = (uint32_t)O0; sO[1] = (uint32_t)(O0 >> 32);
      sO[2] = (uint32_t)O1; sO[3] = (uint32_t)(O1 >> 32);
      sO[4] = (uint32_t)O2; sO[5] = (uint32_t)(O2 >> 32);
    }
  }
  __syncthreads();

  // ---- Phase 4: zero pruned-but-written outputs -------------------------
  {
    uint64_t o0 = ((uint64_t)sO[1] << 32) | sO[0];
    uint64_t o1 = ((uint64_t)sO[3] << 32) | sO[2];
    uint64_t o2 = ((uint64_t)sO[5] << 32) | sO[4];
    const uint32_t* vt32 = (const uint32_t*)vtx;
    for (int w = tid; w < NCH; w += 256) {
      uint64_t pm = sPos[w];
      if (!pm) continue;
      uint64_t p2 = sPos2[w];
      const uint32_t* vp = vt32 + w * 32;
      uint64_t keep = 0ull;
#pragma unroll 8
      for (int j = 0; j < 32; ++j) {
        uint32_t e = vp[j];
        uint64_t k0 = rbit(o0, o1, o2, e & 0xFFu)         & rbit(o0, o1, o2, (e >> 8) & 0xFFu);
        uint64_t k1 = rbit(o0, o1, o2, (e >> 16) & 0xFFu) & rbit(o0, o1, o2, e >> 24);
        keep |= (k0 << (2 * j)) | (k1 << (2 * j + 1));
      }
      uint64_t z = pm & ~(p2 & keep);   // was >0 but pruned -> write 0
      while (z) {
        int i = __builtin_ctzll(z);
        z &= z - 1;
        op[w * 64 + i] = 0.0f;
      }
    }
  }
}

extern "C" void kernel_launch(void* const* d_in, const int* in_sizes, int n_in,
                              void* d_out, int out_size, void* d_ws, size_t ws_size,
                              hipStream_t stream) {
  const float* sp   = (const float*)d_in[0];
  const float* unif = (const float*)d_in[1];
  float* out = (float*)d_out;
  char* ws = (char*)d_ws;
  float2* pw = (float2*)ws;                                        // 263,680 B
  unsigned short* vtx = (unsigned short*)(ws + (size_t)PPAD * 8);  //  65,920 B
  uint64_t* bm = (uint64_t*)(ws + 330752);                         // 4.22 MB
  int bz = in_sizes[1] / PTOT;   // 1024

  init_tables<<<dim3((PPAD + 255) / 256), dim3(256), 0, stream>>>(sp, pw, vtx);
  // 4 waves/block x CPW chunks/wave = 16 chunks/block; 33 blocks cover 515
  sample_kernel<<<dim3((NCH + 4 * CPW - 1) / (4 * CPW), bz), dim3(256), 0, stream>>>(unif, pw, out, bm);
  prune_kernel<<<dim3(bz), dim3(256), 0, stream>>>(bm, vtx, out);
}

// Round 4
// 336.554 us; speedup vs baseline: 1.1052x; 1.0065x over previous
//
#include <hip/hip_runtime.h>
#include <stdint.h>

#define NL   12
#define PTOT 32936
#define LMB  32778
#define NCH  515           // ceil(PTOT/64) words of positivity bits
#define NCHP 520           // padded LDS words
#define NGRP 129           // ceil(NCH/4) 256-elem groups
#define BMW  (NGRP * 4)    // 516 bm words per row (interleaved ballot layout)
#define TPAD (NGRP * 256)  // 33024 padded table elems
#define NGPW 4             // groups per wave in sample kernel

typedef float vf4 __attribute__((ext_vector_type(4)));

__device__ __constant__ int c_base[NL] = {0,86,653,1701,3230,5240,7731,10703,14156,18090,22505,27401};

__device__ __forceinline__ uint64_t ext(const uint64_t* P, uint32_t off) {
  uint32_t w = off >> 6, s = off & 63;
  uint64_t lo = P[w], hi = P[w + 1];
  return s ? ((lo >> s) | (hi << (64 - s))) : lo;
}

__device__ __forceinline__ uint64_t rbit(uint64_t r0, uint64_t r1, uint64_t r2, uint32_t idx) {
  uint64_t w = idx < 64 ? r0 : (idx < 128 ? r1 : r2);
  return (w >> (idx & 63)) & 1ull;
}

__device__ __forceinline__ void orAt(uint64_t& r0, uint64_t& r1, uint64_t& r2,
                                     uint64_t val, uint32_t pos) {
  uint32_t w = pos >> 6, s = pos & 63;
  uint64_t lo = val << s;
  uint64_t hi = s ? (val >> (64 - s)) : 0ull;
  if (w == 0) { r0 |= lo; r1 |= hi; }
  else if (w == 1) { r1 |= lo; r2 |= hi; }
  else { r2 |= lo; }
}

__device__ __forceinline__ void maskLen(uint32_t len, uint64_t& m0, uint64_t& m1, uint64_t& m2) {
  m0 = (len >= 64) ? ~0ull : ((1ull << len) - 1ull);
  m1 = (len <= 64) ? 0ull : ((len >= 128) ? ~0ull : ((1ull << (len - 64)) - 1ull));
  m2 = (len <= 128) ? 0ull : ((1ull << (len - 128)) - 1ull);
}

__device__ __forceinline__ uint32_t ext12(uint64_t O0, uint64_t O1, uint64_t O2, uint32_t pos) {
  uint32_t w = pos >> 6, s = pos & 63;
  uint64_t lo = (w == 0) ? O0 : ((w == 1) ? O1 : O2);
  uint64_t hi = (w == 0) ? O1 : ((w == 1) ? O2 : 0ull);
  uint64_t v = s ? ((lo >> s) | (hi << (64 - s))) : lo;
  return (uint32_t)v & 0xFFFu;
}

// spread 16 bits to every 4th bit of a 64-bit word
__device__ __forceinline__ uint64_t spread4(uint64_t x) {
  x = (x | (x << 24)) & 0x000000FF000000FFull;
  x = (x | (x << 12)) & 0x000F000F000F000Full;
  x = (x | (x << 6))  & 0x0303030303030303ull;
  x = (x | (x << 3))  & 0x1111111111111111ull;
  return x;
}

// Per-param (prob', window) SoA tables + packed (outv|inv<<8) vertex table.
__global__ void init_tables(const float* __restrict__ sp, float* __restrict__ pr,
                            float* __restrict__ wd, unsigned short* __restrict__ vtx) {
  int p = blockIdx.x * blockDim.x + threadIdx.x;
  if (p >= TPAD) return;
  if (p < PTOT) {
    float x = sp[p];
    float s = 1.0f / (1.0f + expf(-x));                 // sigmoid, fp32
    float w = __fmul_rn(s, __fsub_rn(1.0f, s));         // window = p*(1-p)
    float pv = __fadd_rn(__fmul_rn(w, s), __fmul_rn(__fsub_rn(1.0f, w), s));
    pr[p] = pv; wd[p] = w;
    int outv, inv;
    if (p >= LMB) { outv = p - LMB; inv = outv; }
    else {
      int L = 0;
#pragma unroll
      for (int i = 1; i < NL; ++i) if (p >= c_base[i]) L = i;
      int Vq  = 2 + 13 * L;
      int off = p - c_base[L];
      int nq  = 36 * Vq;
      if (off < nq) { int g = off / Vq; inv = off - g * Vq; outv = Vq + (g % 12); }
      else          { outv = Vq + 12; inv = off - nq; }
    }
    vtx[p] = (unsigned short)(outv | (inv << 8));
  } else {
    pr[p] = 0.0f; wd[p] = 1.0f; vtx[p] = 0;
  }
}

// ---- Kernel A: float4 streaming: masks -> out, interleaved pos bits -> bm
__global__ __launch_bounds__(256) void sample_kernel(const float* __restrict__ unif,
                                                     const vf4* __restrict__ pr4,
                                                     const vf4* __restrict__ wd4,
                                                     float* __restrict__ out,
                                                     uint64_t* __restrict__ bm) {
  const int lane = threadIdx.x & 63;
  const int wv   = threadIdx.x >> 6;
  const int row  = blockIdx.y;
  const vf4* up4 = (const vf4*)(unif + (size_t)row * PTOT);
  vf4*       op4 = (vf4*)(out + (size_t)row * PTOT);
  uint64_t*  bp  = bm + (size_t)row * BMW;
  const int g0 = (blockIdx.x * 4 + wv) * NGPW;
#pragma unroll
  for (int k = 0; k < NGPW; ++k) {
    int G = g0 + k;
    if (G >= NGRP) break;
    int e4 = G * 64 + lane;                 // float4 index within row
    bool inb = e4 < (PTOT / 4);             // 8234
    vf4 u = inb ? up4[e4] : (vf4){0.f, 0.f, 0.f, 0.f};
    vf4 p = pr4[e4];                        // padded tables: always safe
    vf4 w = wd4[e4];
    float m0 = __fadd_rn(__fdiv_rn(__fsub_rn(p.x, u.x), w.x), 0.5f);
    float m1 = __fadd_rn(__fdiv_rn(__fsub_rn(p.y, u.y), w.y), 0.5f);
    float m2 = __fadd_rn(__fdiv_rn(__fsub_rn(p.z, u.z), w.z), 0.5f);
    float m3 = __fadd_rn(__fdiv_rn(__fsub_rn(p.w, u.w), w.w), 0.5f);
    if (inb) {
      vf4 o;
      o.x = fminf(fmaxf(m0, 0.0f), 1.0f);
      o.y = fminf(fmaxf(m1, 0.0f), 1.0f);
      o.z = fminf(fmaxf(m2, 0.0f), 1.0f);
      o.w = fminf(fmaxf(m3, 0.0f), 1.0f);
      __builtin_nontemporal_store(o, &op4[e4]);
    }
    uint64_t b0 = __ballot(inb && (m0 > 0.0f));
    uint64_t b1 = __ballot(inb && (m1 > 0.0f));
    uint64_t b2 = __ballot(inb && (m2 > 0.0f));
    uint64_t b3 = __ballot(inb && (m3 > 0.0f));
    if (lane < 4) {
      uint64_t v = (lane == 0) ? b0 : (lane == 1) ? b1 : (lane == 2) ? b2 : b3;
      bp[G * 4 + lane] = v;
    }
  }
}

// ---- Kernel B: per-row graph prune, queue-based coalesced zeroing --------
__global__ __launch_bounds__(256) void prune_kernel(const uint64_t* __restrict__ bm,
                                                    const unsigned short* __restrict__ vtx,
                                                    float* __restrict__ out) {
  __shared__ uint64_t sPos[NCHP];   // pos from original masks (later: z words)
  __shared__ uint64_t sPos2[NCHP];  // pos after forward prune
  __shared__ uint32_t sR[6], sO[6];
  __shared__ int sQn;
  __shared__ unsigned short sQ[NCH];

  const int tid  = threadIdx.x;
  const int lane = tid & 63;
  const int wv   = tid >> 6;
  const int row  = blockIdx.x;
  const uint64_t* bp = bm  + (size_t)row * BMW;
  float*           op = out + (size_t)row * PTOT;

  if (tid == 0) sQn = 0;
  // ---- load + deinterleave ballots into contiguous-bit words -------------
  for (int G = tid; G < NGRP; G += 256) {
    const uint64_t* gp = bp + 4 * G;
    uint64_t b0 = gp[0], b1 = gp[1], b2 = gp[2], b3 = gp[3];
#pragma unroll
    for (int q = 0; q < 4; ++q) {
      uint64_t v = spread4((b0 >> (16 * q)) & 0xFFFFull)
                 | (spread4((b1 >> (16 * q)) & 0xFFFFull) << 1)
                 | (spread4((b2 >> (16 * q)) & 0xFFFFull) << 2)
                 | (spread4((b3 >> (16 * q)) & 0xFFFFull) << 3);
      sPos[4 * G + q] = v; sPos2[4 * G + q] = v;
    }
  }
  for (int w = BMW + tid; w < NCHP; w += 256) { sPos[w] = 0ull; sPos2[w] = 0ull; }
  __syncthreads();

  // ---- Phase 2: forward reachability (wave 0) ---------------------------
  if (tid < 64) {
    uint64_t R0 = 3ull, R1 = 0ull, R2 = 0ull;
    const int g = lane;
#pragma unroll
    for (int L = 0; L < NL; ++L) {
      const int Vq = 2 + 13 * L;
      const int b  = c_base[L];
      bool pred = false;
      if (g < 36) {
        uint32_t off = (uint32_t)(b + g * Vq);
        uint64_t e0 = ext(sPos, off), e1 = ext(sPos, off + 64), e2 = ext(sPos, off + 128);
        pred = ((e0 & R0) | (e1 & R1) | (e2 & R2)) != 0ull;
      }
      uint64_t bal = __ballot(pred);
      uint64_t ar  = bal & (bal >> 12) & (bal >> 24) & 0xFFFull;
      orAt(R0, R1, R2, ar, (uint32_t)Vq);
      const int Vm = Vq + 12;
      uint32_t offm = (uint32_t)(b + 36 * Vq);
      uint64_t e0 = ext(sPos, offm), e1 = ext(sPos, offm + 64), e2 = ext(sPos, offm + 128);
      uint64_t mr = (((e0 & R0) | (e1 & R1) | (e2 & R2)) != 0ull) ? 1ull : 0ull;
      orAt(R0, R1, R2, mr, (uint32_t)Vm);
    }
    if (lane == 0) {
      sR[0] = (uint32_t)R0; sR[1] = (uint32_t)(R0 >> 32);
      sR[2] = (uint32_t)R1; sR[3] = (uint32_t)(R1 >> 32);
      sR[4] = (uint32_t)R2; sR[5] = (uint32_t)(R2 >> 32);
    }
  }
  __syncthreads();

  // ---- Phase 2b: apply forward keep to pos2 -----------------------------
  {
    uint64_t r0 = ((uint64_t)sR[1] << 32) | sR[0];
    uint64_t r1 = ((uint64_t)sR[3] << 32) | sR[2];
    uint64_t r2 = ((uint64_t)sR[5] << 32) | sR[4];
    const uint32_t* vt32 = (const uint32_t*)vtx;
    for (int w = tid; w < NCH; w += 256) {
      uint64_t pm = sPos2[w];
      if (!pm) continue;
      const uint32_t* vp = vt32 + w * 32;
      uint64_t keep = 0ull;
#pragma unroll 8
      for (int j = 0; j < 32; ++j) {
        uint32_t e = vp[j];
        uint64_t k0 = rbit(r0, r1, r2, e & 0xFFu)         & rbit(r0, r1, r2, (e >> 8) & 0xFFu);
        uint64_t k1 = rbit(r0, r1, r2, (e >> 16) & 0xFFu) & rbit(r0, r1, r2, e >> 24);
        keep |= (k0 << (2 * j)) | (k1 << (2 * j + 1));
      }
      sPos2[w] = pm & keep;
    }
  }
  __syncthreads();

  // ---- Phase 3: backward liveness (wave 0) ------------------------------
  if (tid < 64) {
    uint64_t O0 = ext(sPos2, LMB);
    uint64_t O1 = ext(sPos2, LMB + 64);
    uint64_t O2 = ext(sPos2, LMB + 128) & ((1ull << 30) - 1ull);
    const int g  = lane;
    const int hg = g % 12;
#pragma unroll
    for (int L = NL - 1; L >= 0; --L) {
      const int Vq = 2 + 13 * L, Vm = Vq + 12;
      const int b  = c_base[L];
      if (rbit(O0, O1, O2, (uint32_t)Vm)) {
        uint64_t m0, m1, m2; maskLen((uint32_t)Vm, m0, m1, m2);
        uint32_t offm = (uint32_t)(b + 36 * Vq);
        O0 |= ext(sPos2, offm)       & m0;
        O1 |= ext(sPos2, offm + 64)  & m1;
        O2 |= ext(sPos2, offm + 128) & m2;
      }
      uint32_t h12 = ext12(O0, O1, O2, (uint32_t)Vq);
      uint64_t q0, q1, q2; maskLen((uint32_t)Vq, q0, q1, q2);
      uint64_t c0 = 0ull, c1 = 0ull, c2 = 0ull;
      if (g < 36 && ((h12 >> hg) & 1u)) {
        uint32_t off = (uint32_t)(b + g * Vq);
        c0 = ext(sPos2, off)       & q0;
        c1 = ext(sPos2, off + 64)  & q1;
        c2 = ext(sPos2, off + 128) & q2;
      }
#pragma unroll
      for (int d = 32; d; d >>= 1) {
        c0 |= __shfl_xor((unsigned long long)c0, d);
        c1 |= __shfl_xor((unsigned long long)c1, d);
        c2 |= __shfl_xor((unsigned long long)c2, d);
      }
      O0 |= c0; O1 |= c1; O2 |= c2;
    }
    if (lane == 0) {
      sO[0] = (uint32_t)O0; sO[1] = (uint32_t)(O0 >> 32);
      sO[2] = (uint32_t)O1; sO[3] = (uint32_t)(O1 >> 32);
      sO[4] = (uint32_t)O2; sO[5] = (uint32_t)(O2 >> 32);
    }
  }
  __syncthreads();

  // ---- Phase 4: z-words + queue ------------------------------------------
  {
    uint64_t o0 = ((uint64_t)sO[1] << 32) | sO[0];
    uint64_t o1 = ((uint64_t)sO[3] << 32) | sO[2];
    uint64_t o2 = ((uint64_t)sO[5] << 32) | sO[4];
    const uint32_t* vt32 = (const uint32_t*)vtx;
    for (int w = tid; w < NCH; w += 256) {
      uint64_t pm = sPos[w];
      uint64_t z = 0ull;
      if (pm) {
        uint64_t p2 = sPos2[w];
        const uint32_t* vp = vt32 + w * 32;
        uint64_t keep = 0ull;
#pragma unroll 8
        for (int j = 0; j < 32; ++j) {
          uint32_t e = vp[j];
          uint64_t k0 = rbit(o0, o1, o2, e & 0xFFu)         & rbit(o0, o1, o2, (e >> 8) & 0xFFu);
          uint64_t k1 = rbit(o0, o1, o2, (e >> 16) & 0xFFu) & rbit(o0, o1, o2, e >> 24);
          keep |= (k0 << (2 * j)) | (k1 << (2 * j + 1));
        }
        z = pm & ~(p2 & keep);          // was >0 but pruned -> must write 0
      }
      sPos[w] = z;
      if (z) { int k = atomicAdd(&sQn, 1); sQ[k] = (unsigned short)w; }
    }
  }
  __syncthreads();

  // ---- Phase 5: coalesced lane-predicated zero stores --------------------
  {
    const int qn = sQn;
    for (int k = wv; k < qn; k += 4) {
      int w = sQ[k];
      uint64_t z = sPos[w];
      if ((z >> lane) & 1ull) op[w * 64 + lane] = 0.0f;
    }
  }
}

extern "C" void kernel_launch(void* const* d_in, const int* in_sizes, int n_in,
                              void* d_out, int out_size, void* d_ws, size_t ws_size,
                              hipStream_t stream) {
  const float* sp   = (const float*)d_in[0];
  const float* unif = (const float*)d_in[1];
  float* out = (float*)d_out;
  char* ws = (char*)d_ws;
  float* pr = (float*)ws;                                  // 132096 B
  float* wd = (float*)(ws + 132096);                       // 132096 B
  unsigned short* vtx = (unsigned short*)(ws + 264192);    //  66048 B
  uint64_t* bm = (uint64_t*)(ws + 330240);                 // 1024*516*8 B
  int bz = in_sizes[1] / PTOT;   // 1024

  init_tables<<<dim3(TPAD / 256), dim3(256), 0, stream>>>(sp, pr, wd, vtx);
  // 4 waves/block x NGPW groups/wave = 16 groups/block; 9 blocks cover 129
  sample_kernel<<<dim3((NGRP + 4 * NGPW - 1) / (4 * NGPW), bz), dim3(256), 0, stream>>>(
      unif, (const vf4*)pr, (const vf4*)wd, out, bm);
  prune_kernel<<<dim3(bz), dim3(256), 0, stream>>>(bm, vtx, out);
}